// Round 4
// baseline (141.339 us; speedup 1.0000x reference)
//
#include <hip/hip_runtime.h>

#define NB 32
#define NP 4096
#define NM 12
#define NW 9
#define NC 64          // IN_C == OUT_C == 64
#define PN_PAD 4097
#define KDIM (NW * NC)     // 576
#define NKS (KDIM / 16)    // 36 K-steps of the 32x32x16 MFMA
#define KCH 4              // K-chunks in phase 2
#define KSPC (NKS / KCH)   // 9 K-steps per chunk
#define AROW 584           // 576 + 8 pad shorts (16B-aligned rows)
#define PPB 8              // p's per persistent block
#define NBLK (NP / PPB)    // 512 blocks = 2 per CU
#define WROW 144           // floats per p in w2d (12 m * 12 slots)

#define WSW_BYTES (KDIM * NC * 2)            // 73728 B  bf16 swizzled weights
#define W2_OFFSET WSW_BYTES
#define W2_BYTES (NP * WROW * 4)             // 2359296 B  w2d (12 slots/row, 9 used)
#define XB_OFFSET (W2_OFFSET + W2_BYTES)     // 2433024
#define XB_BYTES (NB * PN_PAD * NC * 2)      // 16781312 B  bf16 x
#define WS_NEED ((size_t)XB_OFFSET + XB_BYTES)

typedef __attribute__((ext_vector_type(8))) short short8;
typedef __attribute__((ext_vector_type(2))) float float2v;
typedef __attribute__((ext_vector_type(4))) float float4v;
typedef __attribute__((ext_vector_type(16))) float float16v;

// acc.{lo,hi} += x.{lo,hi} * wp.lo   (VOP3P reg-select broadcast: low reg of pair)
#define PK_FMA_LO(acc, x, wp)                                                  \
    asm("v_pk_fma_f32 %0, %1, %2, %0 op_sel:[0,0,0] op_sel_hi:[1,0,1]"         \
        : "+v"(acc) : "v"(x), "v"(wp))
// acc.{lo,hi} += x.{lo,hi} * wp.hi   (broadcast high reg of pair)
#define PK_FMA_HI(acc, x, wp)                                                  \
    asm("v_pk_fma_f32 %0, %1, %2, %0 op_sel:[0,1,0] op_sel_hi:[1,1,1]"         \
        : "+v"(acc) : "v"(x), "v"(wp))

__device__ __forceinline__ unsigned short f32_to_bf16(float f) {
    union { float f; unsigned u; } v; v.f = f;
    unsigned r = v.u + 0x7FFFu + ((v.u >> 16) & 1u);  // RNE
    return (unsigned short)(r >> 16);
}

// Pack float4 -> 4 bf16 (round via +0x8000, take high 16 bits)
__device__ __forceinline__ uint2 pack_bf16x4(float4v v) {
    union { float f; unsigned u; } a0, a1, a2, a3;
    a0.f = v[0]; a1.f = v[1]; a2.f = v[2]; a3.f = v[3];
    unsigned u0 = a0.u + 0x8000u, u1 = a1.u + 0x8000u;
    unsigned u2 = a2.u + 0x8000u, u3 = a3.u + 0x8000u;
    uint2 r;
    r.x = __builtin_amdgcn_perm(u1, u0, 0x07060302u);
    r.y = __builtin_amdgcn_perm(u3, u2, 0x07060302u);
    return r;
}

// Pack two float2 (lo = ch0,1 / hi = ch2,3) -> 4 bf16
__device__ __forceinline__ uint2 pack_bf16x4_2(float2v lo, float2v hi) {
    union { float f; unsigned u; } a0, a1, a2, a3;
    a0.f = lo[0]; a1.f = lo[1]; a2.f = hi[0]; a3.f = hi[1];
    unsigned u0 = a0.u + 0x8000u, u1 = a1.u + 0x8000u;
    unsigned u2 = a2.u + 0x8000u, u3 = a3.u + 0x8000u;
    uint2 r;
    r.x = __builtin_amdgcn_perm(u1, u0, 0x07060302u);
    r.y = __builtin_amdgcn_perm(u3, u2, 0x07060302u);
    return r;
}

// 4 packed bf16 -> two float2 (bf16->f32 is a 16-bit left shift)
__device__ __forceinline__ void bf16x4_to_2xf2(uint2 u, float2v& lo, float2v& hi) {
    union { unsigned u; float f; } c0, c1, c2, c3;
    c0.u = u.x << 16; c1.u = u.x & 0xFFFF0000u;
    c2.u = u.y << 16; c3.u = u.y & 0xFFFF0000u;
    lo = (float2v){c0.f, c1.f};
    hi = (float2v){c2.f, c3.f};
}

// Fused prep (unchanged, verified):
//  (a) weights fp32 -> bf16 in 32x32x16 MFMA B-fragment order
//  (b) w2d[pm*12 + w] = ww[pm,w] * mask[pm]  (slots 9..11 zeroed)
//  (c) (DOX) x fp32 -> bf16 rows
template<int DOX>
__global__ void prep_all(const float* __restrict__ w,
                         const float* __restrict__ ww,
                         const float* __restrict__ mask,
                         const float* __restrict__ x,
                         unsigned short* __restrict__ wsw,
                         float* __restrict__ w2d,
                         unsigned short* __restrict__ xb) {
    int idx = blockIdx.x * 256 + threadIdx.x;
    if (idx < KDIM * NC) {
        int j    = idx & 7;
        int lane = (idx >> 3) & 63;
        int f    = idx >> 9;       // 0..71  = ks*2 + nt2
        int nt2  = f & 1;
        int ks   = f >> 1;         // 0..35
        int k = ks * 16 + ((lane >> 5) * 8) + j;   // k = w*64 + i
        int n = nt2 * 32 + (lane & 31);            // n = o
        int wi = k >> 6;
        int ii = k & 63;
        wsw[idx] = f32_to_bf16(w[wi * (NC * NC) + n * NC + ii]);
    }
    if (idx < NP * NM * 12) {
        int wq = idx % 12;
        int pm = idx / 12;       // p*12 + m
        float v = 0.f;
        if (wq < NW) v = ww[pm * NW + wq] * mask[pm];
        w2d[idx] = v;
    }
    if (DOX) {
        const int n4 = NB * PN_PAD * NC / 4;  // 2097664
        if (idx < n4) {
            const float4v* x4 = (const float4v*)x;
            ((uint2*)xb)[idx] = pack_bf16x4(x4[idx]);
        }
    }
}

// Persistent block: PPB p's per block, software-pipelined.
// Prologue: stage w2 rows for all PPB p's into LDS (per-(p,m) weights!);
//           prefetch nid + x-gathers for p0.
// Per iteration:
//   [load nid row p+1]
//   phase-1 compute (pk-FMA, per-m LDS weight pairs)   <- xv prefetched last iter
//   bar#1 (prev iter's P reads done) ; write A
//   [readfirstlane nid -> SGPRs; issue xv gathers for p+1]
//   bar#2 ; phase-2: 8 waves, 32x32x16, 4-way K-split
//   bar#3 ; partials->LDS(P reuses A) ; bar#4 ; reduce+bias+store
template<int BF16X>
__global__ __launch_bounds__(512, 4)
void conv_main(const float* __restrict__ x,            // used only when !BF16X
               const unsigned short* __restrict__ xb,  // (32, 4097, 64) bf16
               const unsigned short* __restrict__ wsw,
               const float* __restrict__ bias,
               const float* __restrict__ w2d,
               const int* __restrict__ nid,
               float* __restrict__ out) {
    __shared__ __align__(16) unsigned short A[NB * AROW];   // 37376 B (>= 32 KB partials)
    __shared__ __align__(16) float Wlds[PPB * WROW];        // 4608 B per-(p,m) weights

    const int tid = threadIdx.x;
    const int p0  = blockIdx.x * PPB;

    // phase-1 thread mapping
    const int i4 = tid & 15;   // 4-channel group within the 64-ch row
    const int b  = tid >> 4;   // 0..31
    // phase-2 thread mapping
    const int lane = tid & 63;
    const int wid  = tid >> 6;     // 0..7
    const int nt   = wid & 1;      // N-tile (output channel half)
    const int kc   = wid >> 1;     // K-chunk 0..3
    const int col  = lane & 31;    // A row (= b) and C col within tile
    const int hf   = lane >> 5;
    // reduce mapping
    const int rc  = tid & 31;
    const int rg  = (tid >> 5) & 7;
    const int t2  = tid >> 8;

    const short8* Bfrags = (const short8*)wsw;
    const uint2*  xb2    = (const uint2*)xb;
    const float4v* x4    = (const float4v*)x;

    // ---- prologue ----
    int     nmv[NM];
    uint2   xv[NM];     // BF16X path
    float4v xvf[NM];    // fp32 path
    {
        // stage all PPB weight rows: w2d[p0*WROW .. p0*WROW+1152)
        const float* wsrc = w2d + (size_t)p0 * WROW;
        #pragma unroll
        for (int i = 0; i < 3; ++i) {
            int j = tid + i * 512;
            if (j < PPB * WROW) Wlds[j] = wsrc[j];
        }
        // nid row for p0 -> SGPRs
        const int4* np4 = (const int4*)(nid + p0 * NM);
        int4 nr0 = np4[0], nr1 = np4[1], nr2 = np4[2];
        nmv[0]=__builtin_amdgcn_readfirstlane(nr0.x); nmv[1]=__builtin_amdgcn_readfirstlane(nr0.y);
        nmv[2]=__builtin_amdgcn_readfirstlane(nr0.z); nmv[3]=__builtin_amdgcn_readfirstlane(nr0.w);
        nmv[4]=__builtin_amdgcn_readfirstlane(nr1.x); nmv[5]=__builtin_amdgcn_readfirstlane(nr1.y);
        nmv[6]=__builtin_amdgcn_readfirstlane(nr1.z); nmv[7]=__builtin_amdgcn_readfirstlane(nr1.w);
        nmv[8]=__builtin_amdgcn_readfirstlane(nr2.x); nmv[9]=__builtin_amdgcn_readfirstlane(nr2.y);
        nmv[10]=__builtin_amdgcn_readfirstlane(nr2.z); nmv[11]=__builtin_amdgcn_readfirstlane(nr2.w);
        #pragma unroll
        for (int m = 0; m < NM; ++m) {
            if (BF16X) xv[m]  = xb2[(b * PN_PAD + nmv[m]) * 16 + i4];
            else       xvf[m] = x4 [(b * PN_PAD + nmv[m]) * 16 + i4];
        }
    }
    __syncthreads();   // Wlds staged

    for (int it = 0; it < PPB; ++it) {
        const int p = p0 + it;
        const int havenext = (it + 1 < PPB);

        // issue raw nid loads for next p early (latency hidden by phase-1)
        int4 nr0, nr1, nr2;
        if (havenext) {
            const int4* np4 = (const int4*)(nid + (p + 1) * NM);
            nr0 = np4[0]; nr1 = np4[1]; nr2 = np4[2];
        }

        // ---- phase-1 compute (xv prefetched; per-m weight pairs from LDS) ----
        const float2v* Wl = (const float2v*)(Wlds + it * WROW);  // pair j of m at [m*6+j]
        float2v acc0[NW], acc1[NW];
        #pragma unroll
        for (int w = 0; w < NW; ++w) {
            acc0[w] = (float2v){0.f, 0.f};
            acc1[w] = (float2v){0.f, 0.f};
        }
        #pragma unroll
        for (int m = 0; m < NM; ++m) {
            float2v lo, hi;
            if (BF16X) bf16x4_to_2xf2(xv[m], lo, hi);
            else { lo = (float2v){xvf[m][0], xvf[m][1]}; hi = (float2v){xvf[m][2], xvf[m][3]}; }
            #pragma unroll
            for (int j = 0; j < 4; ++j) {             // w pairs (0,1)(2,3)(4,5)(6,7)
                const float2v wp = Wl[m * 6 + j];     // uniform ds_read_b64 (broadcast)
                PK_FMA_LO(acc0[2 * j],     lo, wp);
                PK_FMA_LO(acc1[2 * j],     hi, wp);
                PK_FMA_HI(acc0[2 * j + 1], lo, wp);
                PK_FMA_HI(acc1[2 * j + 1], hi, wp);
            }
            const float2v wp8 = Wl[m * 6 + 4];        // {w8, 0}
            PK_FMA_LO(acc0[8], lo, wp8);
            PK_FMA_LO(acc1[8], hi, wp8);
        }

        __syncthreads();   // #1: prev iteration's P-region reads complete

        #pragma unroll
        for (int w = 0; w < NW; ++w)
            *(uint2*)&A[b * AROW + w * 64 + i4 * 4] = pack_bf16x4_2(acc0[w], acc1[w]);

        // ---- readfirstlane + issue next-p gathers (covered by ph2 + next ph1 head)
        if (havenext) {
            nmv[0]=__builtin_amdgcn_readfirstlane(nr0.x); nmv[1]=__builtin_amdgcn_readfirstlane(nr0.y);
            nmv[2]=__builtin_amdgcn_readfirstlane(nr0.z); nmv[3]=__builtin_amdgcn_readfirstlane(nr0.w);
            nmv[4]=__builtin_amdgcn_readfirstlane(nr1.x); nmv[5]=__builtin_amdgcn_readfirstlane(nr1.y);
            nmv[6]=__builtin_amdgcn_readfirstlane(nr1.z); nmv[7]=__builtin_amdgcn_readfirstlane(nr1.w);
            nmv[8]=__builtin_amdgcn_readfirstlane(nr2.x); nmv[9]=__builtin_amdgcn_readfirstlane(nr2.y);
            nmv[10]=__builtin_amdgcn_readfirstlane(nr2.z); nmv[11]=__builtin_amdgcn_readfirstlane(nr2.w);
            #pragma unroll
            for (int m = 0; m < NM; ++m) {
                if (BF16X) xv[m]  = xb2[(b * PN_PAD + nmv[m]) * 16 + i4];
                else       xvf[m] = x4 [(b * PN_PAD + nmv[m]) * 16 + i4];
            }
        }

        __syncthreads();   // #2: A tile complete

        // ---- phase-2: 8 waves, 32x32x16 MFMA, 4-way K-split ----
        float16v acc = {0.f,0.f,0.f,0.f, 0.f,0.f,0.f,0.f,
                        0.f,0.f,0.f,0.f, 0.f,0.f,0.f,0.f};
        #pragma unroll
        for (int s = 0; s < KSPC; ++s) {
            const int ks = kc * KSPC + s;
            short8 bfrag = Bfrags[(ks * 2 + nt) * 64 + lane];
            const short8 a = *(const short8*)&A[col * AROW + ks * 16 + hf * 8];
            acc = __builtin_amdgcn_mfma_f32_32x32x16_bf16(a, bfrag, acc, 0, 0, 0);
        }
        __syncthreads();   // #3: all A reads complete before overwrite as P

        float* P = (float*)A;   // P[nt][kc][row(b)][col] f32 = 32 KB
        #pragma unroll
        for (int reg = 0; reg < 16; ++reg) {
            const int row = (reg & 3) + 8 * (reg >> 2) + 4 * hf;
            P[((nt * KCH + kc) * 32 + row) * 32 + col] = acc[reg];
        }
        __syncthreads();   // #4: partials complete

        // reduce 4 partials + bias, coalesced store
        const int o  = t2 * 32 + rc;
        const float bv = bias[o];
        #pragma unroll
        for (int rr = 0; rr < 4; ++rr) {
            const int r = rg * 4 + rr;  // = b
            const float s = P[((t2 * KCH + 0) * 32 + r) * 32 + rc]
                          + P[((t2 * KCH + 1) * 32 + r) * 32 + rc]
                          + P[((t2 * KCH + 2) * 32 + r) * 32 + rc]
                          + P[((t2 * KCH + 3) * 32 + r) * 32 + rc];
            out[(r * NP + p) * NC + o] = s + bv;
        }
        // loop: barrier #1 protects P reads from next iteration's A writes
    }
}

extern "C" void kernel_launch(void* const* d_in, const int* in_sizes, int n_in,
                              void* d_out, int out_size, void* d_ws, size_t ws_size,
                              hipStream_t stream) {
    const float* x    = (const float*)d_in[0];
    const float* w    = (const float*)d_in[1];
    const float* bias = (const float*)d_in[2];
    const float* ww   = (const float*)d_in[3];
    const int*   nid  = (const int*)d_in[4];
    const float* mask = (const float*)d_in[5];
    float* out = (float*)d_out;
    unsigned short* wsw = (unsigned short*)d_ws;
    float* w2d = (float*)((char*)d_ws + W2_OFFSET);
    unsigned short* xb = (unsigned short*)((char*)d_ws + XB_OFFSET);

    if (ws_size >= WS_NEED) {
        const int n4 = NB * PN_PAD * NC / 4;  // 2097664 — sizes the fused prep grid
        hipLaunchKernelGGL(prep_all<1>, dim3((n4 + 255) / 256), dim3(256), 0, stream,
                           w, ww, mask, x, wsw, w2d, xb);
        hipLaunchKernelGGL(conv_main<1>, dim3(NBLK), dim3(512), 0, stream,
                           x, xb, wsw, bias, w2d, nid, out);
    } else {
        const int prep_elems = NP * NM * 12;  // 589824 covers wsw + w2d jobs
        hipLaunchKernelGGL(prep_all<0>, dim3((prep_elems + 255) / 256), dim3(256), 0, stream,
                           w, ww, mask, x, wsw, w2d, xb);
        hipLaunchKernelGGL(conv_main<0>, dim3(NBLK), dim3(512), 0, stream,
                           x, xb, wsw, bias, w2d, nid, out);
    }
}

// Round 5
// 134.361 us; speedup vs baseline: 1.0519x; 1.0519x over previous
//
#include <hip/hip_runtime.h>

#define NB 32
#define NP 4096
#define NM 12
#define NW 9
#define NC 64          // IN_C == OUT_C == 64
#define PN_PAD 4097
#define KDIM (NW * NC)     // 576
#define NKS (KDIM / 16)    // 36 K-steps of the 32x32x16 MFMA
#define AROW 584           // 576 + 8 pad shorts (16B-aligned rows)
#define WROW 144           // floats per p in w2d (12 m * 12 slots)

#define WSW_BYTES (KDIM * NC * 2)            // 73728 B  bf16 swizzled weights
#define W2_OFFSET WSW_BYTES
#define W2_BYTES (NP * WROW * 4)             // 2359296 B  w2d (12 slots/row, 9 used)
#define XB_OFFSET (W2_OFFSET + W2_BYTES)     // 2433024
#define XB_BYTES (NB * PN_PAD * NC * 2)      // 16781312 B  bf16 x
#define WS_NEED ((size_t)XB_OFFSET + XB_BYTES)

typedef __attribute__((ext_vector_type(8))) short short8;
typedef __attribute__((ext_vector_type(2))) float float2v;
typedef __attribute__((ext_vector_type(4))) float float4v;
typedef __attribute__((ext_vector_type(16))) float float16v;

// acc.{lo,hi} += x.{lo,hi} * wp.lo   (VOP3P reg-select broadcast: low reg of pair)
#define PK_FMA_LO(acc, x, wp)                                                  \
    asm("v_pk_fma_f32 %0, %1, %2, %0 op_sel:[0,0,0] op_sel_hi:[1,0,1]"         \
        : "+v"(acc) : "v"(x), "v"(wp))
// acc.{lo,hi} += x.{lo,hi} * wp.hi   (broadcast high reg of pair)
#define PK_FMA_HI(acc, x, wp)                                                  \
    asm("v_pk_fma_f32 %0, %1, %2, %0 op_sel:[0,1,0] op_sel_hi:[1,1,1]"         \
        : "+v"(acc) : "v"(x), "v"(wp))

__device__ __forceinline__ unsigned short f32_to_bf16(float f) {
    union { float f; unsigned u; } v; v.f = f;
    unsigned r = v.u + 0x7FFFu + ((v.u >> 16) & 1u);  // RNE
    return (unsigned short)(r >> 16);
}

// Pack float4 -> 4 bf16 (round via +0x8000, take high 16 bits)
__device__ __forceinline__ uint2 pack_bf16x4(float4v v) {
    union { float f; unsigned u; } a0, a1, a2, a3;
    a0.f = v[0]; a1.f = v[1]; a2.f = v[2]; a3.f = v[3];
    unsigned u0 = a0.u + 0x8000u, u1 = a1.u + 0x8000u;
    unsigned u2 = a2.u + 0x8000u, u3 = a3.u + 0x8000u;
    uint2 r;
    r.x = __builtin_amdgcn_perm(u1, u0, 0x07060302u);
    r.y = __builtin_amdgcn_perm(u3, u2, 0x07060302u);
    return r;
}

// Pack two float2 (lo = ch0,1 / hi = ch2,3) -> 4 bf16
__device__ __forceinline__ uint2 pack_bf16x4_2(float2v lo, float2v hi) {
    union { float f; unsigned u; } a0, a1, a2, a3;
    a0.f = lo[0]; a1.f = lo[1]; a2.f = hi[0]; a3.f = hi[1];
    unsigned u0 = a0.u + 0x8000u, u1 = a1.u + 0x8000u;
    unsigned u2 = a2.u + 0x8000u, u3 = a3.u + 0x8000u;
    uint2 r;
    r.x = __builtin_amdgcn_perm(u1, u0, 0x07060302u);
    r.y = __builtin_amdgcn_perm(u3, u2, 0x07060302u);
    return r;
}

// 4 packed bf16 -> two float2 (bf16->f32 is a 16-bit left shift)
__device__ __forceinline__ void bf16x4_to_2xf2(uint2 u, float2v& lo, float2v& hi) {
    union { unsigned u; float f; } c0, c1, c2, c3;
    c0.u = u.x << 16; c1.u = u.x & 0xFFFF0000u;
    c2.u = u.y << 16; c3.u = u.y & 0xFFFF0000u;
    lo = (float2v){c0.f, c1.f};
    hi = (float2v){c2.f, c3.f};
}

// Fused prep (unchanged, verified):
//  (a) weights fp32 -> bf16 in 32x32x16 MFMA B-fragment order
//  (b) w2d[pm*12 + w] = ww[pm,w] * mask[pm]  (slots 9..11 zeroed)
//  (c) (DOX) x fp32 -> bf16 rows
template<int DOX>
__global__ void prep_all(const float* __restrict__ w,
                         const float* __restrict__ ww,
                         const float* __restrict__ mask,
                         const float* __restrict__ x,
                         unsigned short* __restrict__ wsw,
                         float* __restrict__ w2d,
                         unsigned short* __restrict__ xb) {
    int idx = blockIdx.x * 256 + threadIdx.x;
    if (idx < KDIM * NC) {
        int j    = idx & 7;
        int lane = (idx >> 3) & 63;
        int f    = idx >> 9;       // 0..71  = ks*2 + nt2
        int nt2  = f & 1;
        int ks   = f >> 1;         // 0..35
        int k = ks * 16 + ((lane >> 5) * 8) + j;   // k = w*64 + i
        int n = nt2 * 32 + (lane & 31);            // n = o
        int wi = k >> 6;
        int ii = k & 63;
        wsw[idx] = f32_to_bf16(w[wi * (NC * NC) + n * NC + ii]);
    }
    if (idx < NP * NM * 12) {
        int wq = idx % 12;
        int pm = idx / 12;       // p*12 + m
        float v = 0.f;
        if (wq < NW) v = ww[pm * NW + wq] * mask[pm];
        w2d[idx] = v;
    }
    if (DOX) {
        const int n4 = NB * PN_PAD * NC / 4;  // 2097664
        if (idx < n4) {
            const float4v* x4 = (const float4v*)x;
            ((uint2*)xb)[idx] = pack_bf16x4(x4[idx]);
        }
    }
}

// One block (512 threads) per p.  [R1 structure + pk-FMA phase-1]
// Phase 0: issue x-gathers; stage this p's 144 weight floats into LDS; barrier.
// Phase 1: t[b, w*64+i] (32 x 576) fp32 acc via v_pk_fma_f32 (weight pairs
//          broadcast from LDS) -> bf16 LDS tile.
// Phase 2: 2 waves, each one 32x32x16-MFMA N-tile over K=576 (wsw read 1x/block).
template<int BF16X>
__global__ __launch_bounds__(512)
void conv_main(const float* __restrict__ x,            // used only when !BF16X
               const unsigned short* __restrict__ xb,  // (32, 4097, 64) bf16
               const unsigned short* __restrict__ wsw,
               const float* __restrict__ bias,
               const float* __restrict__ w2d,
               const int* __restrict__ nid,
               float* __restrict__ out) {
    __shared__ __align__(16) unsigned short A[NB * AROW];
    __shared__ __align__(16) float Wlds[WROW];   // 576 B: this p's w2 row

    const int p = blockIdx.x;
    const int tid = threadIdx.x;

    // ---- Phase 1 ----
    {
        const int i4 = tid & 15;   // 4-channel group within the 64-ch row
        const int b  = tid >> 4;   // 0..31
        const int* nidp = nid + p * NM;

        int nm[NM];
        #pragma unroll
        for (int m = 0; m < NM; ++m) nm[m] = nidp[m];  // uniform -> SGPRs

        // issue the 12 gathers first (long-latency), then stage weights
        uint2 xv[NM];
        float4v xvf[NM];
        if (BF16X) {
            const uint2* xb2 = (const uint2*)xb;   // row = 16 uint2 (128 B)
            #pragma unroll
            for (int m = 0; m < NM; ++m)
                xv[m] = xb2[(b * PN_PAD + nm[m]) * 16 + i4];
        } else {
            const float4v* x4 = (const float4v*)x;
            #pragma unroll
            for (int m = 0; m < NM; ++m)
                xvf[m] = x4[(b * PN_PAD + nm[m]) * 16 + i4];
        }

        if (tid < WROW) Wlds[tid] = w2d[p * WROW + tid];
        __syncthreads();           // Wlds staged (also covers gather latency)

        float2v acc0[NW], acc1[NW];
        #pragma unroll
        for (int w = 0; w < NW; ++w) {
            acc0[w] = (float2v){0.f, 0.f};
            acc1[w] = (float2v){0.f, 0.f};
        }

        #pragma unroll
        for (int m = 0; m < NM; ++m) {
            float2v lo, hi;
            if (BF16X) bf16x4_to_2xf2(xv[m], lo, hi);
            else { lo = (float2v){xvf[m][0], xvf[m][1]}; hi = (float2v){xvf[m][2], xvf[m][3]}; }
            // weight pairs for this m: 48 B = b128 + b128 + b64, uniform broadcast
            const float4v w03 = ((const float4v*)Wlds)[m * 3 + 0];  // pairs 0,1
            const float4v w47 = ((const float4v*)Wlds)[m * 3 + 1];  // pairs 2,3
            const float2v w8  = ((const float2v*)Wlds)[m * 6 + 4];  // pair 4 = {w8, 0}
            const float2v wp0 = {w03[0], w03[1]}, wp1 = {w03[2], w03[3]};
            const float2v wp2 = {w47[0], w47[1]}, wp3 = {w47[2], w47[3]};
            PK_FMA_LO(acc0[0], lo, wp0);  PK_FMA_LO(acc1[0], hi, wp0);
            PK_FMA_HI(acc0[1], lo, wp0);  PK_FMA_HI(acc1[1], hi, wp0);
            PK_FMA_LO(acc0[2], lo, wp1);  PK_FMA_LO(acc1[2], hi, wp1);
            PK_FMA_HI(acc0[3], lo, wp1);  PK_FMA_HI(acc1[3], hi, wp1);
            PK_FMA_LO(acc0[4], lo, wp2);  PK_FMA_LO(acc1[4], hi, wp2);
            PK_FMA_HI(acc0[5], lo, wp2);  PK_FMA_HI(acc1[5], hi, wp2);
            PK_FMA_LO(acc0[6], lo, wp3);  PK_FMA_LO(acc1[6], hi, wp3);
            PK_FMA_HI(acc0[7], lo, wp3);  PK_FMA_HI(acc1[7], hi, wp3);
            PK_FMA_LO(acc0[8], lo, w8);   PK_FMA_LO(acc1[8], hi, w8);
        }

        #pragma unroll
        for (int w = 0; w < NW; ++w)
            *(uint2*)&A[b * AROW + w * 64 + i4 * 4] = pack_bf16x4_2(acc0[w], acc1[w]);
    }
    __syncthreads();

    // ---- Phase 2 : 2 waves, 32x32x16 MFMA ----
    {
        const int lane = tid & 63;
        const int wid  = tid >> 6;
        if (wid < 2) {
            const int col  = lane & 31;   // A row (= b) and C col within tile
            const int half = lane >> 5;   // k-subgroup
            float16v acc = {0.f,0.f,0.f,0.f, 0.f,0.f,0.f,0.f,
                            0.f,0.f,0.f,0.f, 0.f,0.f,0.f,0.f};
            const short8* Bfrags = (const short8*)wsw;

            #pragma unroll
            for (int ks = 0; ks < NKS; ++ks) {
                short8 bfrag = Bfrags[(ks * 2 + wid) * 64 + lane];
                const short8 a = *(const short8*)&A[col * AROW + ks * 16 + half * 8];
                acc = __builtin_amdgcn_mfma_f32_32x32x16_bf16(a, bfrag, acc, 0, 0, 0);
            }

            const int o = wid * 32 + col;
            const float bv = bias[o];
            // C/D layout (HW-verified): col=lane&31, row=(reg&3)+8*(reg>>2)+4*(lane>>5)
            #pragma unroll
            for (int reg = 0; reg < 16; ++reg) {
                const int b = (reg & 3) + 8 * (reg >> 2) + 4 * half;
                out[(b * NP + p) * NC + o] = acc[reg] + bv;
            }
        }
    }
}

extern "C" void kernel_launch(void* const* d_in, const int* in_sizes, int n_in,
                              void* d_out, int out_size, void* d_ws, size_t ws_size,
                              hipStream_t stream) {
    const float* x    = (const float*)d_in[0];
    const float* w    = (const float*)d_in[1];
    const float* bias = (const float*)d_in[2];
    const float* ww   = (const float*)d_in[3];
    const int*   nid  = (const int*)d_in[4];
    const float* mask = (const float*)d_in[5];
    float* out = (float*)d_out;
    unsigned short* wsw = (unsigned short*)d_ws;
    float* w2d = (float*)((char*)d_ws + W2_OFFSET);
    unsigned short* xb = (unsigned short*)((char*)d_ws + XB_OFFSET);

    if (ws_size >= WS_NEED) {
        const int n4 = NB * PN_PAD * NC / 4;  // 2097664 — sizes the fused prep grid
        hipLaunchKernelGGL(prep_all<1>, dim3((n4 + 255) / 256), dim3(256), 0, stream,
                           w, ww, mask, x, wsw, w2d, xb);
        hipLaunchKernelGGL(conv_main<1>, dim3(NP), dim3(512), 0, stream,
                           x, xb, wsw, bias, w2d, nid, out);
    } else {
        const int prep_elems = NP * NM * 12;  // 589824 covers wsw + w2d jobs
        hipLaunchKernelGGL(prep_all<0>, dim3((prep_elems + 255) / 256), dim3(256), 0, stream,
                           w, ww, mask, x, wsw, w2d, xb);
        hipLaunchKernelGGL(conv_main<0>, dim3(NP), dim3(512), 0, stream,
                           x, xb, wsw, bias, w2d, nid, out);
    }
}

// Round 6
// 132.077 us; speedup vs baseline: 1.0701x; 1.0173x over previous
//
#include <hip/hip_runtime.h>

#define NB 32
#define NP 4096
#define NM 12
#define NW 9
#define NC 64          // IN_C == OUT_C == 64
#define PN_PAD 4097
#define KDIM (NW * NC)     // 576
#define NKS (KDIM / 16)    // 36 K-steps of the 32x32x16 MFMA
#define KCH 4              // K-chunks in phase 2
#define KSPC (NKS / KCH)   // 9 K-steps per chunk
#define AROW 584           // 576 + 8 pad shorts (16B-aligned rows)
#define WROW 144           // floats per p in w2d (12 m * 12 slots)

#define WSW_BYTES (KDIM * NC * 2)            // 73728 B  bf16 swizzled weights
#define W2_OFFSET WSW_BYTES
#define W2_BYTES (NP * WROW * 4)             // 2359296 B  w2d (12 slots/row, 9 used)
#define XB_OFFSET (W2_OFFSET + W2_BYTES)     // 2433024
#define XB_BYTES (NB * PN_PAD * NC * 2)      // 16781312 B  bf16 x
#define WS_NEED ((size_t)XB_OFFSET + XB_BYTES)

typedef __attribute__((ext_vector_type(8))) short short8;
typedef __attribute__((ext_vector_type(2))) float float2v;
typedef __attribute__((ext_vector_type(4))) float float4v;
typedef __attribute__((ext_vector_type(16))) float float16v;

__device__ __forceinline__ unsigned short f32_to_bf16(float f) {
    union { float f; unsigned u; } v; v.f = f;
    unsigned r = v.u + 0x7FFFu + ((v.u >> 16) & 1u);  // RNE
    return (unsigned short)(r >> 16);
}

// Pack float4 -> 4 bf16 (round via +0x8000, take high 16 bits)
__device__ __forceinline__ uint2 pack_bf16x4(float4v v) {
    union { float f; unsigned u; } a0, a1, a2, a3;
    a0.f = v[0]; a1.f = v[1]; a2.f = v[2]; a3.f = v[3];
    unsigned u0 = a0.u + 0x8000u, u1 = a1.u + 0x8000u;
    unsigned u2 = a2.u + 0x8000u, u3 = a3.u + 0x8000u;
    uint2 r;
    r.x = __builtin_amdgcn_perm(u1, u0, 0x07060302u);
    r.y = __builtin_amdgcn_perm(u3, u2, 0x07060302u);
    return r;
}

// Pack two float2 (lo = ch0,1 / hi = ch2,3) -> 4 bf16
__device__ __forceinline__ uint2 pack_bf16x4_2(float2v lo, float2v hi) {
    union { float f; unsigned u; } a0, a1, a2, a3;
    a0.f = lo[0]; a1.f = lo[1]; a2.f = hi[0]; a3.f = hi[1];
    unsigned u0 = a0.u + 0x8000u, u1 = a1.u + 0x8000u;
    unsigned u2 = a2.u + 0x8000u, u3 = a3.u + 0x8000u;
    uint2 r;
    r.x = __builtin_amdgcn_perm(u1, u0, 0x07060302u);
    r.y = __builtin_amdgcn_perm(u3, u2, 0x07060302u);
    return r;
}

// 4 packed bf16 -> two float2 (bf16->f32 is a 16-bit left shift)
__device__ __forceinline__ void bf16x4_to_2xf2(uint2 u, float2v& lo, float2v& hi) {
    union { unsigned u; float f; } c0, c1, c2, c3;
    c0.u = u.x << 16; c1.u = u.x & 0xFFFF0000u;
    c2.u = u.y << 16; c3.u = u.y & 0xFFFF0000u;
    lo = (float2v){c0.f, c1.f};
    hi = (float2v){c2.f, c3.f};
}

// Fused prep (unchanged, verified):
//  (a) weights fp32 -> bf16 in 32x32x16 MFMA B-fragment order
//  (b) w2d[pm*12 + w] = ww[pm,w] * mask[pm]  (slots 9..11 zeroed)
//  (c) (DOX) x fp32 -> bf16 rows
template<int DOX>
__global__ void prep_all(const float* __restrict__ w,
                         const float* __restrict__ ww,
                         const float* __restrict__ mask,
                         const float* __restrict__ x,
                         unsigned short* __restrict__ wsw,
                         float* __restrict__ w2d,
                         unsigned short* __restrict__ xb) {
    int idx = blockIdx.x * 256 + threadIdx.x;
    if (idx < KDIM * NC) {
        int j    = idx & 7;
        int lane = (idx >> 3) & 63;
        int f    = idx >> 9;       // 0..71  = ks*2 + nt2
        int nt2  = f & 1;
        int ks   = f >> 1;         // 0..35
        int k = ks * 16 + ((lane >> 5) * 8) + j;   // k = w*64 + i
        int n = nt2 * 32 + (lane & 31);            // n = o
        int wi = k >> 6;
        int ii = k & 63;
        wsw[idx] = f32_to_bf16(w[wi * (NC * NC) + n * NC + ii]);
    }
    if (idx < NP * NM * 12) {
        int wq = idx % 12;
        int pm = idx / 12;       // p*12 + m
        float v = 0.f;
        if (wq < NW) v = ww[pm * NW + wq] * mask[pm];
        w2d[idx] = v;
    }
    if (DOX) {
        const int n4 = NB * PN_PAD * NC / 4;  // 2097664
        if (idx < n4) {
            const float4v* x4 = (const float4v*)x;
            ((uint2*)xb)[idx] = pack_bf16x4(x4[idx]);
        }
    }
}

// One block (512 threads) per p.
// Phase 1 (R1-verbatim, 46.4 champion): t[b, w*64+i] (32 x 576) fp32 acc,
//   scalar FMA with uniform-global weight loads (compiler -> s_load + v_fmac).
// Phase 2 (R2-verbatim): ALL 8 waves, 32x32x16 MFMA, 4-way K-split;
//   partials -> LDS (reusing A region) -> reduce + bias + store.  wsw read 1x.
template<int BF16X>
__global__ __launch_bounds__(512)
void conv_main(const float* __restrict__ x,            // used only when !BF16X
               const unsigned short* __restrict__ xb,  // (32, 4097, 64) bf16
               const unsigned short* __restrict__ wsw,
               const float* __restrict__ bias,
               const float* __restrict__ w2d,
               const int* __restrict__ nid,
               float* __restrict__ out) {
    __shared__ __align__(16) unsigned short A[NB * AROW];   // 37376 B (>= 32 KB partials)

    const int p = blockIdx.x;
    const int tid = threadIdx.x;

    // ---- Phase 1 (R1 structure) ----
    {
        const int i4 = tid & 15;   // 4-channel group within the 64-ch row
        const int b  = tid >> 4;   // 0..31
        const float* w2p = w2d + p * WROW;
        const int* nidp = nid + p * NM;

        int nm[NM];
        #pragma unroll
        for (int m = 0; m < NM; ++m) nm[m] = nidp[m];  // uniform -> SGPRs

        float2v acc0[NW], acc1[NW];
        #pragma unroll
        for (int w = 0; w < NW; ++w) {
            acc0[w] = (float2v){0.f, 0.f};
            acc1[w] = (float2v){0.f, 0.f};
        }

        if (BF16X) {
            const uint2* xb2 = (const uint2*)xb;   // row = 16 uint2 (128 B)
            uint2 xv[NM];
            #pragma unroll
            for (int m = 0; m < NM; ++m)
                xv[m] = xb2[(b * PN_PAD + nm[m]) * 16 + i4];
            #pragma unroll
            for (int m = 0; m < NM; ++m) {
                float2v lo, hi;
                bf16x4_to_2xf2(xv[m], lo, hi);
                #pragma unroll
                for (int w = 0; w < NW; ++w) {
                    const float ws = w2p[m * 12 + w];   // uniform -> scalar load
                    acc0[w] += lo * ws;
                    acc1[w] += hi * ws;
                }
            }
        } else {
            const float4v* x4 = (const float4v*)x;
            float4v xv[NM];
            #pragma unroll
            for (int m = 0; m < NM; ++m)
                xv[m] = x4[(b * PN_PAD + nm[m]) * 16 + i4];
            #pragma unroll
            for (int m = 0; m < NM; ++m) {
                const float2v lo = {xv[m][0], xv[m][1]};
                const float2v hi = {xv[m][2], xv[m][3]};
                #pragma unroll
                for (int w = 0; w < NW; ++w) {
                    const float ws = w2p[m * 12 + w];
                    acc0[w] += lo * ws;
                    acc1[w] += hi * ws;
                }
            }
        }

        #pragma unroll
        for (int w = 0; w < NW; ++w)
            *(uint2*)&A[b * AROW + w * 64 + i4 * 4] = pack_bf16x4_2(acc0[w], acc1[w]);
    }
    __syncthreads();

    // ---- Phase 2 (R2 structure): 8 waves, 32x32x16 MFMA, 4-way K-split ----
    {
        const int lane = tid & 63;
        const int wid  = tid >> 6;     // 0..7
        const int nt   = wid & 1;      // N-tile (output channel half)
        const int kc   = wid >> 1;     // K-chunk 0..3
        const int col  = lane & 31;    // A row (= b) and C col within tile
        const int hf   = lane >> 5;

        float16v acc = {0.f,0.f,0.f,0.f, 0.f,0.f,0.f,0.f,
                        0.f,0.f,0.f,0.f, 0.f,0.f,0.f,0.f};
        const short8* Bfrags = (const short8*)wsw;

        #pragma unroll
        for (int s = 0; s < KSPC; ++s) {
            const int ks = kc * KSPC + s;
            short8 bfrag = Bfrags[(ks * 2 + nt) * 64 + lane];
            const short8 a = *(const short8*)&A[col * AROW + ks * 16 + hf * 8];
            acc = __builtin_amdgcn_mfma_f32_32x32x16_bf16(a, bfrag, acc, 0, 0, 0);
        }
        __syncthreads();               // all A reads complete

        // partials into LDS (reuse A region): P[nt][kc][row(b)][col] f32 = 32 KB
        float* P = (float*)A;
        #pragma unroll
        for (int reg = 0; reg < 16; ++reg) {
            const int row = (reg & 3) + 8 * (reg >> 2) + 4 * hf;
            P[((nt * KCH + kc) * 32 + row) * 32 + col] = acc[reg];
        }
        __syncthreads();

        // reduce 4 partials + bias, coalesced store
        const int c  = tid & 31;
        const int rg = (tid >> 5) & 7;
        const int t2 = tid >> 8;       // which N-tile
        const int o  = t2 * 32 + c;
        const float bv = bias[o];
        #pragma unroll
        for (int rr = 0; rr < 4; ++rr) {
            const int r = rg * 4 + rr;  // = b
            const float s = P[((t2 * KCH + 0) * 32 + r) * 32 + c]
                          + P[((t2 * KCH + 1) * 32 + r) * 32 + c]
                          + P[((t2 * KCH + 2) * 32 + r) * 32 + c]
                          + P[((t2 * KCH + 3) * 32 + r) * 32 + c];
            out[(r * NP + p) * NC + o] = s + bv;
        }
    }
}

extern "C" void kernel_launch(void* const* d_in, const int* in_sizes, int n_in,
                              void* d_out, int out_size, void* d_ws, size_t ws_size,
                              hipStream_t stream) {
    const float* x    = (const float*)d_in[0];
    const float* w    = (const float*)d_in[1];
    const float* bias = (const float*)d_in[2];
    const float* ww   = (const float*)d_in[3];
    const int*   nid  = (const int*)d_in[4];
    const float* mask = (const float*)d_in[5];
    float* out = (float*)d_out;
    unsigned short* wsw = (unsigned short*)d_ws;
    float* w2d = (float*)((char*)d_ws + W2_OFFSET);
    unsigned short* xb = (unsigned short*)((char*)d_ws + XB_OFFSET);

    if (ws_size >= WS_NEED) {
        const int n4 = NB * PN_PAD * NC / 4;  // 2097664 — sizes the fused prep grid
        hipLaunchKernelGGL(prep_all<1>, dim3((n4 + 255) / 256), dim3(256), 0, stream,
                           w, ww, mask, x, wsw, w2d, xb);
        hipLaunchKernelGGL(conv_main<1>, dim3(NP), dim3(512), 0, stream,
                           x, xb, wsw, bias, w2d, nid, out);
    } else {
        const int prep_elems = NP * NM * 12;  // 589824 covers wsw + w2d jobs
        hipLaunchKernelGGL(prep_all<0>, dim3((prep_elems + 255) / 256), dim3(256), 0, stream,
                           w, ww, mask, x, wsw, w2d, xb);
        hipLaunchKernelGGL(conv_main<0>, dim3(NP), dim3(512), 0, stream,
                           x, xb, wsw, bias, w2d, nid, out);
    }
}